// Round 1
// baseline (2412.919 us; speedup 1.0000x reference)
//
#include <hip/hip_runtime.h>

#define DIM 64
#define TWO_DIM 128

__device__ __forceinline__ float fast_tanh(float x) {
  float cx = fminf(fmaxf(x, -15.0f), 15.0f);
  float e = __expf(2.0f * cx);
  return (e - 1.0f) / (e + 1.0f);
}

// histogram: cnt[idx[i]] += 1
__global__ void k_hist(const int* __restrict__ idx, int* __restrict__ cnt, int n) {
  int i = blockIdx.x * blockDim.x + threadIdx.x;
  if (i < n) atomicAdd(&cnt[idx[i]], 1);
}

// single-block exclusive scan of deg[0..n) -> offs, cursor (copy)
__global__ void k_scan(const int* __restrict__ deg, int* __restrict__ offs,
                       int* __restrict__ cursor, int n, int chunk) {
  __shared__ int part[1024];
  int t = threadIdx.x;
  int lo = t * chunk, hi = min(lo + chunk, n);
  int s = 0;
  for (int i = lo; i < hi; ++i) s += deg[i];
  part[t] = s;
  __syncthreads();
  for (int off = 1; off < 1024; off <<= 1) {
    int v = (t >= off) ? part[t - off] : 0;
    __syncthreads();
    part[t] += v;
    __syncthreads();
  }
  int run = part[t] - s;  // exclusive prefix of this thread's chunk
  for (int i = lo; i < hi; ++i) {
    offs[i] = run;
    cursor[i] = run;
    run += deg[i];
  }
}

__global__ void k_scatter(const int* __restrict__ src, const int* __restrict__ dst,
                          int* __restrict__ cursor, int* __restrict__ csr, int E) {
  int e = blockIdx.x * blockDim.x + threadIdx.x;
  if (e < E) {
    int p = atomicAdd(&cursor[dst[e]], 1);
    csr[p] = src[e];
  }
}

// one 64-lane wave per node; lane = feature. agg[n][t] = sum over in-edges x[src][t]
__global__ void k_gather(const float* __restrict__ x, const int* __restrict__ csr,
                         const int* __restrict__ offs, const int* __restrict__ deg,
                         float* __restrict__ agg, int n) {
  int node = blockIdx.x * 4 + (threadIdx.x >> 6);
  int t = threadIdx.x & 63;
  if (node >= n) return;
  int s = offs[node], d = deg[node];
  float acc = 0.0f;
  for (int base = 0; base < d; base += 64) {
    int m = min(64, d - base);
    int myi = (t < m) ? csr[s + base + t] : 0;
    for (int i = 0; i < m; ++i) {
      int sn = __shfl(myi, i);
      acc += x[(size_t)sn * DIM + t];
    }
  }
  agg[(size_t)node * DIM + t] = acc;
}

// transpose W1 [64][128] -> W1T [128][64]; fold BN(eval) into scale/shift
__global__ void k_prep(const float* __restrict__ W1, const float* __restrict__ b1,
                       const float* __restrict__ gamma, const float* __restrict__ beta,
                       float* __restrict__ W1T, float* __restrict__ sc,
                       float* __restrict__ sh) {
  int i = blockIdx.x * blockDim.x + threadIdx.x;
  if (i < TWO_DIM * DIM) {
    int j = i / DIM, k = i % DIM;
    W1T[j * DIM + k] = W1[k * TWO_DIM + j];
  }
  if (i < TWO_DIM) {
    float s = gamma[i] * rsqrtf(1.0f + 1e-5f);
    sc[i] = s;
    sh[i] = b1[i] * s + beta[i];
  }
}

// one thread per node: full GIN MLP. POOL: atomically accumulate tanh output
// into pooled[batch[node]] instead of writing hout.
template <bool POOL>
__global__ void k_mlp(const float* __restrict__ xin, const float* __restrict__ agg,
                      const float* __restrict__ epsp,
                      const float* __restrict__ W1T, const float* __restrict__ sc,
                      const float* __restrict__ sh, const float* __restrict__ W2,
                      const float* __restrict__ b2, float* __restrict__ hout,
                      float* __restrict__ pooled, const int* __restrict__ batch,
                      int n) {
  int node = blockIdx.x * blockDim.x + threadIdx.x;
  if (node >= n) return;
  float ep = 1.0f + epsp[0];
  float v[DIM];
  const float4* x4 = reinterpret_cast<const float4*>(xin + (size_t)node * DIM);
  const float4* a4 = reinterpret_cast<const float4*>(agg + (size_t)node * DIM);
#pragma unroll
  for (int q = 0; q < DIM / 4; ++q) {
    float4 xv = x4[q];
    float4 av = a4[q];
    v[4 * q + 0] = ep * xv.x + av.x;
    v[4 * q + 1] = ep * xv.y + av.y;
    v[4 * q + 2] = ep * xv.z + av.z;
    v[4 * q + 3] = ep * xv.w + av.w;
  }
  float z[DIM];
#pragma unroll
  for (int i = 0; i < DIM; ++i) z[i] = 0.0f;
#pragma unroll 2
  for (int j = 0; j < TWO_DIM; ++j) {
    float acc = 0.0f;
    const float* __restrict__ w1 = W1T + j * DIM;  // uniform addr -> s_load
#pragma unroll
    for (int k = 0; k < DIM; ++k) acc += v[k] * w1[k];
    float tj = fast_tanh(acc * sc[j] + sh[j]);
    const float* __restrict__ w2 = W2 + j * DIM;   // uniform addr -> s_load
#pragma unroll
    for (int i = 0; i < DIM; ++i) z[i] += tj * w2[i];
  }
  if (POOL) {
    int b = batch[node];
#pragma unroll
    for (int i = 0; i < DIM; ++i) {
      float o = fast_tanh(z[i] + b2[i]);
      atomicAdd(&pooled[(size_t)b * DIM + i], o);
    }
  } else {
    float4* h4 = reinterpret_cast<float4*>(hout + (size_t)node * DIM);
#pragma unroll
    for (int q = 0; q < DIM / 4; ++q) {
      float4 o;
      o.x = fast_tanh(z[4 * q + 0] + b2[4 * q + 0]);
      o.y = fast_tanh(z[4 * q + 1] + b2[4 * q + 1]);
      o.z = fast_tanh(z[4 * q + 2] + b2[4 * q + 2]);
      o.w = fast_tanh(z[4 * q + 3] + b2[4 * q + 3]);
      h4[q] = o;
    }
  }
}

// out[g][i] = tanh( (pooled[g]/max(cnt,1)) . linW[:,i] + linb[i] )
__global__ void k_out(const float* __restrict__ pooled, const int* __restrict__ cnt,
                      const float* __restrict__ linW, const float* __restrict__ linb,
                      float* __restrict__ out) {
  int g = blockIdx.x;
  int i = threadIdx.x;
  int c = cnt[g];
  float inv = 1.0f / (float)(c > 0 ? c : 1);
  float acc = 0.0f;
#pragma unroll
  for (int k = 0; k < DIM; ++k)
    acc += pooled[(size_t)g * DIM + k] * linW[k * DIM + i];
  out[(size_t)g * DIM + i] = fast_tanh(acc * inv + linb[i]);
}

extern "C" void kernel_launch(void* const* d_in, const int* in_sizes, int n_in,
                              void* d_out, int out_size, void* d_ws, size_t ws_size,
                              hipStream_t stream) {
  const float* x = (const float*)d_in[0];
  const int* ei = (const int*)d_in[1];
  const int* batch = (const int*)d_in[2];
  const float* eps1 = (const float*)d_in[3];
  const float* W11 = (const float*)d_in[4];
  const float* b11 = (const float*)d_in[5];
  const float* g1 = (const float*)d_in[6];
  const float* be1 = (const float*)d_in[7];
  const float* W12 = (const float*)d_in[8];
  const float* b12 = (const float*)d_in[9];
  const float* eps2 = (const float*)d_in[10];
  const float* W21 = (const float*)d_in[11];
  const float* b21 = (const float*)d_in[12];
  const float* g2 = (const float*)d_in[13];
  const float* be2 = (const float*)d_in[14];
  const float* W22 = (const float*)d_in[15];
  const float* b22 = (const float*)d_in[16];
  const float* linW = (const float*)d_in[17];
  const float* linb = (const float*)d_in[18];

  const int n = in_sizes[0] / DIM;       // 100000
  const int E = in_sizes[1] / 2;         // 1600000
  const int G = out_size / DIM;          // 256
  const int* src = ei;
  const int* dst = ei + E;

  size_t off = 0;
  auto alloc = [&](size_t bytes) -> void* {
    void* p = (char*)d_ws + off;
    off += (bytes + 255) & ~(size_t)255;
    return p;
  };
  float* agg = (float*)alloc((size_t)n * DIM * 4);
  float* h1 = (float*)alloc((size_t)n * DIM * 4);
  int* deg = (int*)alloc((size_t)n * 4);
  int* offs = (int*)alloc((size_t)n * 4);
  int* cursor = (int*)alloc((size_t)n * 4);
  int* csr = (int*)alloc((size_t)E * 4);
  float* W1T1 = (float*)alloc(TWO_DIM * DIM * 4);
  float* sc1 = (float*)alloc(TWO_DIM * 4);
  float* sh1 = (float*)alloc(TWO_DIM * 4);
  float* W1T2 = (float*)alloc(TWO_DIM * DIM * 4);
  float* sc2 = (float*)alloc(TWO_DIM * 4);
  float* sh2 = (float*)alloc(TWO_DIM * 4);
  float* pooled = (float*)alloc((size_t)G * DIM * 4);
  int* cnt = (int*)alloc((size_t)G * 4);

  hipMemsetAsync(deg, 0, (size_t)n * 4, stream);
  hipMemsetAsync(cnt, 0, (size_t)G * 4, stream);
  hipMemsetAsync(pooled, 0, (size_t)G * DIM * 4, stream);

  k_hist<<<(E + 255) / 256, 256, 0, stream>>>(dst, deg, E);
  k_hist<<<(n + 255) / 256, 256, 0, stream>>>(batch, cnt, n);
  k_scan<<<1, 1024, 0, stream>>>(deg, offs, cursor, n, (n + 1023) / 1024);
  k_scatter<<<(E + 255) / 256, 256, 0, stream>>>(src, dst, cursor, csr, E);
  k_prep<<<(TWO_DIM * DIM + 255) / 256, 256, 0, stream>>>(W11, b11, g1, be1, W1T1,
                                                          sc1, sh1);
  k_prep<<<(TWO_DIM * DIM + 255) / 256, 256, 0, stream>>>(W21, b21, g2, be2, W1T2,
                                                          sc2, sh2);

  k_gather<<<(n + 3) / 4, 256, 0, stream>>>(x, csr, offs, deg, agg, n);
  k_mlp<false><<<(n + 63) / 64, 64, 0, stream>>>(x, agg, eps1, W1T1, sc1, sh1, W12,
                                                 b12, h1, nullptr, nullptr, n);
  k_gather<<<(n + 3) / 4, 256, 0, stream>>>(h1, csr, offs, deg, agg, n);
  k_mlp<true><<<(n + 63) / 64, 64, 0, stream>>>(h1, agg, eps2, W1T2, sc2, sh2, W22,
                                                b22, nullptr, pooled, batch, n);
  k_out<<<G, DIM, 0, stream>>>(pooled, cnt, linW, linb, (float*)d_out);
}

// Round 2
// 1702.042 us; speedup vs baseline: 1.4177x; 1.4177x over previous
//
#include <hip/hip_runtime.h>

#define DIM 64
#define TWO_DIM 128

__device__ __forceinline__ float fast_tanh(float x) {
  float cx = fminf(fmaxf(x, -15.0f), 15.0f);
  float e = __expf(2.0f * cx);
  return (e - 1.0f) / (e + 1.0f);
}

// histogram: cnt[idx[i]] += 1
__global__ void k_hist(const int* __restrict__ idx, int* __restrict__ cnt, int n) {
  int i = blockIdx.x * blockDim.x + threadIdx.x;
  if (i < n) atomicAdd(&cnt[idx[i]], 1);
}

// single-block exclusive scan of deg[0..n) -> offs, cursor (copy)
__global__ void k_scan(const int* __restrict__ deg, int* __restrict__ offs,
                       int* __restrict__ cursor, int n, int chunk) {
  __shared__ int part[1024];
  int t = threadIdx.x;
  int lo = t * chunk, hi = min(lo + chunk, n);
  int s = 0;
  for (int i = lo; i < hi; ++i) s += deg[i];
  part[t] = s;
  __syncthreads();
  for (int off = 1; off < 1024; off <<= 1) {
    int v = (t >= off) ? part[t - off] : 0;
    __syncthreads();
    part[t] += v;
    __syncthreads();
  }
  int run = part[t] - s;  // exclusive prefix of this thread's chunk
  for (int i = lo; i < hi; ++i) {
    offs[i] = run;
    cursor[i] = run;
    run += deg[i];
  }
}

__global__ void k_scatter(const int* __restrict__ src, const int* __restrict__ dst,
                          int* __restrict__ cursor, int* __restrict__ csr, int E) {
  int e = blockIdx.x * blockDim.x + threadIdx.x;
  if (e < E) {
    int p = atomicAdd(&cursor[dst[e]], 1);
    csr[p] = src[e];
  }
}

// one 64-lane wave per node; lane = feature. agg[n][t] = sum over in-edges x[src][t]
__global__ void k_gather(const float* __restrict__ x, const int* __restrict__ csr,
                         const int* __restrict__ offs, const int* __restrict__ deg,
                         float* __restrict__ agg, int n) {
  int node = blockIdx.x * 4 + (threadIdx.x >> 6);
  int t = threadIdx.x & 63;
  if (node >= n) return;
  int s = offs[node], d = deg[node];
  float acc = 0.0f;
  for (int base = 0; base < d; base += 64) {
    int m = min(64, d - base);
    int myi = (t < m) ? csr[s + base + t] : 0;
    for (int i = 0; i < m; ++i) {
      int sn = __shfl(myi, i);
      acc += x[(size_t)sn * DIM + t];
    }
  }
  agg[(size_t)node * DIM + t] = acc;
}

// transpose W1 [64][128] -> W1T [128][64]; fold BN(eval) into scale/shift
__global__ void k_prep(const float* __restrict__ W1, const float* __restrict__ b1,
                       const float* __restrict__ gamma, const float* __restrict__ beta,
                       float* __restrict__ W1T, float* __restrict__ sc,
                       float* __restrict__ sh) {
  int i = blockIdx.x * blockDim.x + threadIdx.x;
  if (i < TWO_DIM * DIM) {
    int j = i / DIM, k = i % DIM;
    W1T[j * DIM + k] = W1[k * TWO_DIM + j];
  }
  if (i < TWO_DIM) {
    float s = gamma[i] * rsqrtf(1.0f + 1e-5f);
    sc[i] = s;
    sh[i] = b1[i] * s + beta[i];
  }
}

// one thread per node: full GIN MLP, weights staged in LDS (broadcast reads).
// POOL: atomically accumulate tanh output into pooled[batch[node]].
template <bool POOL>
__launch_bounds__(256, 2)
__global__ void k_mlp(const float* __restrict__ xin, const float* __restrict__ agg,
                      const float* __restrict__ epsp,
                      const float* __restrict__ W1T, const float* __restrict__ sc,
                      const float* __restrict__ sh, const float* __restrict__ W2,
                      const float* __restrict__ b2, float* __restrict__ hout,
                      float* __restrict__ pooled, const int* __restrict__ batch,
                      int n) {
  __shared__ float sW1[TWO_DIM * DIM];   // 32 KB
  __shared__ float sW2[TWO_DIM * DIM];   // 32 KB
  __shared__ float ssc[TWO_DIM], ssh[TWO_DIM], sb2[DIM];

  int t = threadIdx.x;
  // stage weights (float4, all threads participate BEFORE any return)
  const float4* gW1 = reinterpret_cast<const float4*>(W1T);
  const float4* gW2 = reinterpret_cast<const float4*>(W2);
  float4* lW1 = reinterpret_cast<float4*>(sW1);
  float4* lW2 = reinterpret_cast<float4*>(sW2);
#pragma unroll
  for (int q = 0; q < (TWO_DIM * DIM / 4) / 256; ++q) {
    int i = q * 256 + t;
    lW1[i] = gW1[i];
    lW2[i] = gW2[i];
  }
  if (t < TWO_DIM) {
    ssc[t] = sc[t];
    ssh[t] = sh[t];
  }
  if (t < DIM) sb2[t] = b2[t];
  __syncthreads();

  int node = blockIdx.x * blockDim.x + t;
  if (node >= n) return;

  float ep = 1.0f + epsp[0];
  float v[DIM];
  const float4* x4 = reinterpret_cast<const float4*>(xin + (size_t)node * DIM);
  const float4* a4 = reinterpret_cast<const float4*>(agg + (size_t)node * DIM);
#pragma unroll
  for (int q = 0; q < DIM / 4; ++q) {
    float4 xv = x4[q];
    float4 av = a4[q];
    v[4 * q + 0] = ep * xv.x + av.x;
    v[4 * q + 1] = ep * xv.y + av.y;
    v[4 * q + 2] = ep * xv.z + av.z;
    v[4 * q + 3] = ep * xv.w + av.w;
  }
  float z[DIM];
#pragma unroll
  for (int i = 0; i < DIM; ++i) z[i] = 0.0f;

#pragma unroll 2
  for (int j = 0; j < TWO_DIM; ++j) {
    // dot(v, W1T row j) with 2 partial accumulators for ILP
    const float4* w1 = reinterpret_cast<const float4*>(sW1 + j * DIM);
    float acc0 = 0.0f, acc1 = 0.0f;
#pragma unroll
    for (int q = 0; q < DIM / 8; ++q) {
      float4 wa = w1[2 * q];
      float4 wb = w1[2 * q + 1];
      acc0 += v[8 * q + 0] * wa.x + v[8 * q + 1] * wa.y +
              v[8 * q + 2] * wa.z + v[8 * q + 3] * wa.w;
      acc1 += v[8 * q + 4] * wb.x + v[8 * q + 5] * wb.y +
              v[8 * q + 6] * wb.z + v[8 * q + 7] * wb.w;
    }
    float tj = fast_tanh((acc0 + acc1) * ssc[j] + ssh[j]);
    const float4* w2 = reinterpret_cast<const float4*>(sW2 + j * DIM);
#pragma unroll
    for (int q = 0; q < DIM / 4; ++q) {
      float4 wv = w2[q];
      z[4 * q + 0] += tj * wv.x;
      z[4 * q + 1] += tj * wv.y;
      z[4 * q + 2] += tj * wv.z;
      z[4 * q + 3] += tj * wv.w;
    }
  }

  if (POOL) {
    int b = batch[node];
#pragma unroll
    for (int i = 0; i < DIM; ++i) {
      float o = fast_tanh(z[i] + sb2[i]);
      atomicAdd(&pooled[(size_t)b * DIM + i], o);
    }
  } else {
    float4* h4 = reinterpret_cast<float4*>(hout + (size_t)node * DIM);
#pragma unroll
    for (int q = 0; q < DIM / 4; ++q) {
      float4 o;
      o.x = fast_tanh(z[4 * q + 0] + sb2[4 * q + 0]);
      o.y = fast_tanh(z[4 * q + 1] + sb2[4 * q + 1]);
      o.z = fast_tanh(z[4 * q + 2] + sb2[4 * q + 2]);
      o.w = fast_tanh(z[4 * q + 3] + sb2[4 * q + 3]);
      h4[q] = o;
    }
  }
}

// out[g][i] = tanh( (pooled[g]/max(cnt,1)) . linW[:,i] + linb[i] )
__global__ void k_out(const float* __restrict__ pooled, const int* __restrict__ cnt,
                      const float* __restrict__ linW, const float* __restrict__ linb,
                      float* __restrict__ out) {
  int g = blockIdx.x;
  int i = threadIdx.x;
  int c = cnt[g];
  float inv = 1.0f / (float)(c > 0 ? c : 1);
  float acc = 0.0f;
#pragma unroll
  for (int k = 0; k < DIM; ++k)
    acc += pooled[(size_t)g * DIM + k] * linW[k * DIM + i];
  out[(size_t)g * DIM + i] = fast_tanh(acc * inv + linb[i]);
}

extern "C" void kernel_launch(void* const* d_in, const int* in_sizes, int n_in,
                              void* d_out, int out_size, void* d_ws, size_t ws_size,
                              hipStream_t stream) {
  const float* x = (const float*)d_in[0];
  const int* ei = (const int*)d_in[1];
  const int* batch = (const int*)d_in[2];
  const float* eps1 = (const float*)d_in[3];
  const float* W11 = (const float*)d_in[4];
  const float* b11 = (const float*)d_in[5];
  const float* g1 = (const float*)d_in[6];
  const float* be1 = (const float*)d_in[7];
  const float* W12 = (const float*)d_in[8];
  const float* b12 = (const float*)d_in[9];
  const float* eps2 = (const float*)d_in[10];
  const float* W21 = (const float*)d_in[11];
  const float* b21 = (const float*)d_in[12];
  const float* g2 = (const float*)d_in[13];
  const float* be2 = (const float*)d_in[14];
  const float* W22 = (const float*)d_in[15];
  const float* b22 = (const float*)d_in[16];
  const float* linW = (const float*)d_in[17];
  const float* linb = (const float*)d_in[18];

  const int n = in_sizes[0] / DIM;       // 100000
  const int E = in_sizes[1] / 2;         // 1600000
  const int G = out_size / DIM;          // 256
  const int* src = ei;
  const int* dst = ei + E;

  size_t off = 0;
  auto alloc = [&](size_t bytes) -> void* {
    void* p = (char*)d_ws + off;
    off += (bytes + 255) & ~(size_t)255;
    return p;
  };
  float* agg = (float*)alloc((size_t)n * DIM * 4);
  float* h1 = (float*)alloc((size_t)n * DIM * 4);
  int* deg = (int*)alloc((size_t)n * 4);
  int* offs = (int*)alloc((size_t)n * 4);
  int* cursor = (int*)alloc((size_t)n * 4);
  int* csr = (int*)alloc((size_t)E * 4);
  float* W1T1 = (float*)alloc(TWO_DIM * DIM * 4);
  float* sc1 = (float*)alloc(TWO_DIM * 4);
  float* sh1 = (float*)alloc(TWO_DIM * 4);
  float* W1T2 = (float*)alloc(TWO_DIM * DIM * 4);
  float* sc2 = (float*)alloc(TWO_DIM * 4);
  float* sh2 = (float*)alloc(TWO_DIM * 4);
  float* pooled = (float*)alloc((size_t)G * DIM * 4);
  int* cnt = (int*)alloc((size_t)G * 4);

  hipMemsetAsync(deg, 0, (size_t)n * 4, stream);
  hipMemsetAsync(cnt, 0, (size_t)G * 4, stream);
  hipMemsetAsync(pooled, 0, (size_t)G * DIM * 4, stream);

  k_hist<<<(E + 255) / 256, 256, 0, stream>>>(dst, deg, E);
  k_hist<<<(n + 255) / 256, 256, 0, stream>>>(batch, cnt, n);
  k_scan<<<1, 1024, 0, stream>>>(deg, offs, cursor, n, (n + 1023) / 1024);
  k_scatter<<<(E + 255) / 256, 256, 0, stream>>>(src, dst, cursor, csr, E);
  k_prep<<<(TWO_DIM * DIM + 255) / 256, 256, 0, stream>>>(W11, b11, g1, be1, W1T1,
                                                          sc1, sh1);
  k_prep<<<(TWO_DIM * DIM + 255) / 256, 256, 0, stream>>>(W21, b21, g2, be2, W1T2,
                                                          sc2, sh2);

  k_gather<<<(n + 3) / 4, 256, 0, stream>>>(x, csr, offs, deg, agg, n);
  k_mlp<false><<<(n + 255) / 256, 256, 0, stream>>>(x, agg, eps1, W1T1, sc1, sh1,
                                                    W12, b12, h1, nullptr, nullptr,
                                                    n);
  k_gather<<<(n + 3) / 4, 256, 0, stream>>>(h1, csr, offs, deg, agg, n);
  k_mlp<true><<<(n + 255) / 256, 256, 0, stream>>>(h1, agg, eps2, W1T2, sc2, sh2,
                                                   W22, b22, nullptr, pooled, batch,
                                                   n);
  k_out<<<G, DIM, 0, stream>>>(pooled, cnt, linW, linb, (float*)d_out);
}